// Round 1
// baseline (596.698 us; speedup 1.0000x reference)
//
#include <hip/hip_runtime.h>

// Problem constants
#define N_TOK 4096   // H*W
#define C_DIM 256
#define D_DIM 32
#define B_SZ  4

typedef float f32x4 __attribute__((ext_vector_type(4)));
typedef short short8 __attribute__((ext_vector_type(8)));
typedef short short4v __attribute__((ext_vector_type(4)));
typedef unsigned short u16;

__device__ __forceinline__ u16 f2bf(float f) {
    unsigned int u = __builtin_bit_cast(unsigned int, f);
    u += 0x7fffu + ((u >> 16) & 1u);   // round-to-nearest-even
    return (u16)(u >> 16);
}
__device__ __forceinline__ float bf2f(u16 h) {
    unsigned int u = ((unsigned int)h) << 16;
    return __builtin_bit_cast(float, u);
}

// ---------------------------------------------------------------------------
// Kernel 1: q/k projection.  q = wq*x1 (+bq), k = wk*x2 (+bk)
// Output layout: Q[slice][i][d], K[slice][j][d]  (d contiguous, bf16)
// grid (64 i-tiles, 16 = qk*8 + branch*4 + b), block 256
// ---------------------------------------------------------------------------
__global__ __launch_bounds__(256) void qk_proj(
    const float* __restrict__ x1, const float* __restrict__ x2,
    const float* __restrict__ wq1, const float* __restrict__ bq1,
    const float* __restrict__ wk1, const float* __restrict__ bk1,
    const float* __restrict__ wq2, const float* __restrict__ bq2,
    const float* __restrict__ wk2, const float* __restrict__ bk2,
    u16* __restrict__ wsQ, u16* __restrict__ wsK)
{
    __shared__ float w_lds[32 * 256];
    const int ib = blockIdx.x;
    const int comb = blockIdx.y;
    const int b = comb & 3;
    const int branch = (comb >> 2) & 1;
    const int qk = comb >> 3;

    const float* x = qk ? x2 : x1;           // q from x1; k from x2
    const float* w; const float* bias; u16* dst;
    if (qk == 0) { w = branch ? wq2 : wq1; bias = branch ? bq2 : bq1; dst = wsQ; }
    else         { w = branch ? wk2 : wk1; bias = branch ? bk2 : bk1; dst = wsK; }
    const int slice = branch * 4 + b;
    dst += (size_t)slice * N_TOK * D_DIM;

    const int tid = threadIdx.x;
    for (int t = tid; t < 32 * 256; t += 256) w_lds[t] = w[t];
    __syncthreads();

    const int il = tid & 63;
    const int db = tid >> 6;                 // 0..3 -> d = db*8 + mm
    const float* xc = x + (size_t)b * C_DIM * N_TOK + ib * 64 + il;

    float acc[8] = {0.f,0.f,0.f,0.f,0.f,0.f,0.f,0.f};
    for (int c4 = 0; c4 < 256; c4 += 4) {
        const float xv0 = xc[(size_t)(c4 + 0) * N_TOK];
        const float xv1 = xc[(size_t)(c4 + 1) * N_TOK];
        const float xv2 = xc[(size_t)(c4 + 2) * N_TOK];
        const float xv3 = xc[(size_t)(c4 + 3) * N_TOK];
#pragma unroll
        for (int mm = 0; mm < 8; ++mm) {
            const float4 wv = *(const float4*)&w_lds[(db * 8 + mm) * 256 + c4];
            acc[mm] += xv0 * wv.x + xv1 * wv.y + xv2 * wv.z + xv3 * wv.w;
        }
    }
    short8 pack;
#pragma unroll
    for (int mm = 0; mm < 8; ++mm)
        pack[mm] = (short)f2bf(acc[mm] + bias[db * 8 + mm]);
    *(short8*)(dst + (size_t)(ib * 64 + il) * D_DIM + db * 8) = pack;
}

// ---------------------------------------------------------------------------
// Kernel 2: v projection.  v = wv*x2 (+bv).  Output layout V[slice][c][j]
// grid (64 j-tiles, 4 c-tiles, 8 slices), block 256
// ---------------------------------------------------------------------------
__global__ __launch_bounds__(256) void v_proj(
    const float* __restrict__ x2,
    const float* __restrict__ wv1, const float* __restrict__ bv1,
    const float* __restrict__ wv2, const float* __restrict__ bv2,
    u16* __restrict__ wsV)
{
    __shared__ float w_lds[64 * 128];
    const int jt = blockIdx.x;
    const int ct = blockIdx.y;
    const int s  = blockIdx.z;
    const int branch = s >> 2, b = s & 3;
    const float* w    = branch ? wv2 : wv1;
    const float* bias = branch ? bv2 : bv1;
    u16* dst = wsV + (size_t)s * C_DIM * N_TOK;

    const int tid = threadIdx.x;
    const int jl = tid & 63;
    const int cb = tid >> 6;                 // 0..3 -> c = ct*64 + cb*16 + mm
    const float* xc = x2 + (size_t)b * C_DIM * N_TOK + jt * 64 + jl;

    float acc[16];
#pragma unroll
    for (int mm = 0; mm < 16; ++mm) acc[mm] = 0.f;

    for (int p = 0; p < 2; ++p) {
        __syncthreads();
        for (int t = tid; t < 64 * 128; t += 256) {
            const int row = t >> 7, col = t & 127;
            w_lds[t] = w[(size_t)(ct * 64 + row) * 256 + p * 128 + col];
        }
        __syncthreads();
        for (int c4 = 0; c4 < 128; c4 += 4) {
            const float xv0 = xc[(size_t)(p * 128 + c4 + 0) * N_TOK];
            const float xv1 = xc[(size_t)(p * 128 + c4 + 1) * N_TOK];
            const float xv2 = xc[(size_t)(p * 128 + c4 + 2) * N_TOK];
            const float xv3 = xc[(size_t)(p * 128 + c4 + 3) * N_TOK];
#pragma unroll
            for (int mm = 0; mm < 16; ++mm) {
                const float4 wv = *(const float4*)&w_lds[(cb * 16 + mm) * 128 + c4];
                acc[mm] += xv0 * wv.x + xv1 * wv.y + xv2 * wv.z + xv3 * wv.w;
            }
        }
    }
#pragma unroll
    for (int mm = 0; mm < 16; ++mm) {
        const int c = ct * 64 + cb * 16 + mm;
        dst[(size_t)c * N_TOK + jt * 64 + jl] = f2bf(acc[mm] + bias[c]);
    }
}

// ---------------------------------------------------------------------------
// Kernel 3: flash attention (swapped QK^T so softmax rows are lane-local).
// Q,K: [slice][row][32] bf16 ; V: [slice][c][j] bf16 ; O: [slice][i][c] bf16
// grid (64 i-tiles, 8 slices), block 256 (4 waves, 16 i-rows each)
// ---------------------------------------------------------------------------
__device__ __forceinline__ void stage_v(const u16* vslice, short* lds_dst_base,
                                        int wave, int lane, int j0)
{
#pragma unroll
    for (int ii = 0; ii < 4; ++ii) {
        const int crow = wave * 64 + ii * 16;
        const u16* gp = vslice + (size_t)(crow + (lane >> 2)) * N_TOK + j0 + (lane & 3) * 8;
        short* lp = lds_dst_base + crow * 32;   // 32 shorts (64B) per c-row
        __builtin_amdgcn_global_load_lds(
            (const __attribute__((address_space(1))) void*)gp,
            (__attribute__((address_space(3))) void*)lp, 16, 0, 0);
    }
}

__global__ __launch_bounds__(256) void attn_fwd(
    const u16* __restrict__ Q, const u16* __restrict__ K,
    const u16* __restrict__ V, u16* __restrict__ O)
{
    __shared__ short vlds[2 * 8192];   // 2 x (32 j x 256 c) bf16 = 32 KB

    const int s  = blockIdx.y;
    const int ib = blockIdx.x;
    const u16* q = Q + (size_t)s * N_TOK * D_DIM;
    const u16* k = K + (size_t)s * N_TOK * D_DIM;
    const u16* v = V + (size_t)s * C_DIM * N_TOK;
    u16*       o = O + (size_t)s * N_TOK * C_DIM;

    const int tid  = threadIdx.x;
    const int wave = tid >> 6;
    const int lane = tid & 63;
    const int g    = lane >> 4;
    const int li   = lane & 15;
    const int i0   = ib * 64 + wave * 16;

    // Q fragment (B operand): lane li -> row i0+li, d = 8g..8g+7 (contiguous 16B)
    const short8 qf = *(const short8*)(q + (size_t)(i0 + li) * D_DIM + 8 * g);

    f32x4 acc[16];
#pragma unroll
    for (int cf = 0; cf < 16; ++cf) acc[cf] = (f32x4){0.f, 0.f, 0.f, 0.f};
    float m = -3.0e38f, lsum = 0.f;

    stage_v(v, vlds, wave, lane, 0);
    __syncthreads();

    int buf = 0;
    for (int t = 0; t < N_TOK / 32; ++t) {
        if (t < N_TOK / 32 - 1) stage_v(v, vlds + (buf ^ 1) * 8192, wave, lane, (t + 1) * 32);
        const int j0 = t * 32;

        // S^T = K * Q^T : D[j-row][i-col], i = li lane-local
        const short8 kf0 = *(const short8*)(k + (size_t)(j0 + li) * D_DIM + 8 * g);
        const short8 kf1 = *(const short8*)(k + (size_t)(j0 + 16 + li) * D_DIM + 8 * g);
        const f32x4 z = (f32x4){0.f, 0.f, 0.f, 0.f};
        f32x4 s0 = __builtin_amdgcn_mfma_f32_16x16x32_bf16(kf0, qf, z, 0, 0, 0);
        f32x4 s1 = __builtin_amdgcn_mfma_f32_16x16x32_bf16(kf1, qf, z, 0, 0, 0);

        // online softmax for column i = li (8 j-values per lane)
        float pm = fmaxf(fmaxf(fmaxf(s0[0], s0[1]), fmaxf(s0[2], s0[3])),
                         fmaxf(fmaxf(s1[0], s1[1]), fmaxf(s1[2], s1[3])));
        pm = fmaxf(pm, __shfl_xor(pm, 16));
        pm = fmaxf(pm, __shfl_xor(pm, 32));

        if (__any(pm > m + 8.0f)) {          // T13 defer-max: P bounded by e^8
            const float mn = fmaxf(m, pm);
            const float sc = __expf(m - mn);
            m = mn;
            lsum *= sc;
            float scr[4];
#pragma unroll
            for (int r = 0; r < 4; ++r) scr[r] = __shfl(sc, 4 * g + r);
#pragma unroll
            for (int cf = 0; cf < 16; ++cf)
#pragma unroll
                for (int r = 0; r < 4; ++r) acc[cf][r] *= scr[r];
        }

        float p[8];
#pragma unroll
        for (int r = 0; r < 4; ++r) { p[r] = __expf(s0[r] - m); p[4 + r] = __expf(s1[r] - m); }
        float rs = (p[0] + p[1]) + (p[2] + p[3]) + (p[4] + p[5]) + (p[6] + p[7]);
        rs += __shfl_xor(rs, 16);
        rs += __shfl_xor(rs, 32);
        lsum += rs;

        // P -> bf16 A-fragment, in-register (elems 0-3 = j0+4g+r, 4-7 = j0+16+4g+r)
        short8 pa;
#pragma unroll
        for (int jj = 0; jj < 8; ++jj) pa[jj] = (short)f2bf(p[jj]);

        // O += P * V^T
        const int vb = buf * 8192;
#pragma unroll
        for (int cf = 0; cf < 16; ++cf) {
            const int ro = vb + (cf * 16 + li) * 32 + g * 4;
            const short4v lo = *(const short4v*)&vlds[ro];
            const short4v hi = *(const short4v*)&vlds[ro + 16];
            const short8 vf = {lo[0], lo[1], lo[2], lo[3], hi[0], hi[1], hi[2], hi[3]};
            acc[cf] = __builtin_amdgcn_mfma_f32_16x16x32_bf16(pa, vf, acc[cf], 0, 0, 0);
        }
        __syncthreads();
        buf ^= 1;
    }

    // normalize and store O[i][c]
    const float linv = 1.0f / lsum;
    float lr[4];
#pragma unroll
    for (int r = 0; r < 4; ++r) lr[r] = __shfl(linv, 4 * g + r);
#pragma unroll
    for (int cf = 0; cf < 16; ++cf)
#pragma unroll
        for (int r = 0; r < 4; ++r)
            o[(size_t)(i0 + 4 * g + r) * C_DIM + cf * 16 + li] = f2bf(acc[cf][r] * lr[r]);
}

// ---------------------------------------------------------------------------
// Kernel 4: out[b][c][i] = x1 + x2 + O1[b][i][c] + O2[b][i][c]  (LDS transpose)
// grid (64 i-tiles, 4 c-tiles, 4 b), block 256
// ---------------------------------------------------------------------------
__global__ __launch_bounds__(256) void epilogue(
    const float* __restrict__ x1, const float* __restrict__ x2,
    const u16* __restrict__ O, float* __restrict__ out)
{
    __shared__ float tl[64][65];
    const int it = blockIdx.x, ct = blockIdx.y, b = blockIdx.z;
    const int tid = threadIdx.x;
    const int cl = tid & 63, r0 = tid >> 6;

    const u16* O1 = O + (size_t)(b)     * N_TOK * C_DIM;
    const u16* O2 = O + (size_t)(4 + b) * N_TOK * C_DIM;

#pragma unroll
    for (int rr = 0; rr < 16; ++rr) {
        const int il = r0 + rr * 4;
        const size_t off = (size_t)(it * 64 + il) * C_DIM + ct * 64 + cl;
        tl[il][cl] = bf2f(O1[off]) + bf2f(O2[off]);
    }
    __syncthreads();
#pragma unroll
    for (int rr = 0; rr < 16; ++rr) {
        const int c2 = r0 + rr * 4;
        const size_t idx = ((size_t)b * C_DIM + ct * 64 + c2) * N_TOK + it * 64 + cl;
        out[idx] = x1[idx] + x2[idx] + tl[cl][c2];
    }
}

// ---------------------------------------------------------------------------
extern "C" void kernel_launch(void* const* d_in, const int* in_sizes, int n_in,
                              void* d_out, int out_size, void* d_ws, size_t ws_size,
                              hipStream_t stream)
{
    const float* x1  = (const float*)d_in[0];
    const float* x2  = (const float*)d_in[1];
    const float* wq1 = (const float*)d_in[2];
    const float* bq1 = (const float*)d_in[3];
    const float* wk1 = (const float*)d_in[4];
    const float* bk1 = (const float*)d_in[5];
    const float* wv1 = (const float*)d_in[6];
    const float* bv1 = (const float*)d_in[7];
    const float* wq2 = (const float*)d_in[8];
    const float* bq2 = (const float*)d_in[9];
    const float* wk2 = (const float*)d_in[10];
    const float* bk2 = (const float*)d_in[11];
    const float* wv2 = (const float*)d_in[12];
    const float* bv2 = (const float*)d_in[13];
    float* out = (float*)d_out;

    // ws layout (bf16 elements): Q[8][4096][32] | K[8][4096][32] | V[8][256][4096] | O[8][4096][256]
    // total = (1M + 1M + 8M + 8M) shorts = 36 MB
    u16* wsQ = (u16*)d_ws;
    u16* wsK = wsQ + (size_t)8 * N_TOK * D_DIM;
    u16* wsV = wsK + (size_t)8 * N_TOK * D_DIM;
    u16* wsO = wsV + (size_t)8 * C_DIM * N_TOK;

    qk_proj<<<dim3(64, 16), 256, 0, stream>>>(x1, x2, wq1, bq1, wk1, bk1,
                                              wq2, bq2, wk2, bk2, wsQ, wsK);
    v_proj<<<dim3(64, 4, 8), 256, 0, stream>>>(x2, wv1, bv1, wv2, bv2, wsV);
    attn_fwd<<<dim3(64, 8), 256, 0, stream>>>(wsQ, wsK, wsV, wsO);
    epilogue<<<dim3(64, 4, 4), 256, 0, stream>>>(x1, x2, wsO, out);
}

// Round 2
// 389.184 us; speedup vs baseline: 1.5332x; 1.5332x over previous
//
#include <hip/hip_runtime.h>

// Problem constants
#define N_TOK 4096   // H*W
#define C_DIM 256
#define D_DIM 32
#define B_SZ  4

typedef float f32x4 __attribute__((ext_vector_type(4)));
typedef short short8 __attribute__((ext_vector_type(8)));
typedef short short4v __attribute__((ext_vector_type(4)));
typedef unsigned short u16;

__device__ __forceinline__ u16 f2bf(float f) {
    unsigned int u = __builtin_bit_cast(unsigned int, f);
    u += 0x7fffu + ((u >> 16) & 1u);   // round-to-nearest-even
    return (u16)(u >> 16);
}
__device__ __forceinline__ float bf2f(u16 h) {
    unsigned int u = ((unsigned int)h) << 16;
    return __builtin_bit_cast(float, u);
}

// ---------------------------------------------------------------------------
// Kernel 1: q/k projection.  q = wq*x1 (+bq), k = wk*x2 (+bk)
// Output layout: Q[slice][i][d], K[slice][j][d]  (d contiguous, bf16)
// ---------------------------------------------------------------------------
__global__ __launch_bounds__(256) void qk_proj(
    const float* __restrict__ x1, const float* __restrict__ x2,
    const float* __restrict__ wq1, const float* __restrict__ bq1,
    const float* __restrict__ wk1, const float* __restrict__ bk1,
    const float* __restrict__ wq2, const float* __restrict__ bq2,
    const float* __restrict__ wk2, const float* __restrict__ bk2,
    u16* __restrict__ wsQ, u16* __restrict__ wsK)
{
    __shared__ float w_lds[32 * 256];
    const int ib = blockIdx.x;
    const int comb = blockIdx.y;
    const int b = comb & 3;
    const int branch = (comb >> 2) & 1;
    const int qk = comb >> 3;

    const float* x = qk ? x2 : x1;           // q from x1; k from x2
    const float* w; const float* bias; u16* dst;
    if (qk == 0) { w = branch ? wq2 : wq1; bias = branch ? bq2 : bq1; dst = wsQ; }
    else         { w = branch ? wk2 : wk1; bias = branch ? bk2 : bk1; dst = wsK; }
    const int slice = branch * 4 + b;
    dst += (size_t)slice * N_TOK * D_DIM;

    const int tid = threadIdx.x;
    for (int t = tid; t < 32 * 256; t += 256) w_lds[t] = w[t];
    __syncthreads();

    const int il = tid & 63;
    const int db = tid >> 6;                 // 0..3 -> d = db*8 + mm
    const float* xc = x + (size_t)b * C_DIM * N_TOK + ib * 64 + il;

    float acc[8] = {0.f,0.f,0.f,0.f,0.f,0.f,0.f,0.f};
    for (int c4 = 0; c4 < 256; c4 += 4) {
        const float xv0 = xc[(size_t)(c4 + 0) * N_TOK];
        const float xv1 = xc[(size_t)(c4 + 1) * N_TOK];
        const float xv2 = xc[(size_t)(c4 + 2) * N_TOK];
        const float xv3 = xc[(size_t)(c4 + 3) * N_TOK];
#pragma unroll
        for (int mm = 0; mm < 8; ++mm) {
            const float4 wv = *(const float4*)&w_lds[(db * 8 + mm) * 256 + c4];
            acc[mm] += xv0 * wv.x + xv1 * wv.y + xv2 * wv.z + xv3 * wv.w;
        }
    }
    short8 pack;
#pragma unroll
    for (int mm = 0; mm < 8; ++mm)
        pack[mm] = (short)f2bf(acc[mm] + bias[db * 8 + mm]);
    *(short8*)(dst + (size_t)(ib * 64 + il) * D_DIM + db * 8) = pack;
}

// ---------------------------------------------------------------------------
// Kernel 2: v projection.  v = wv*x2 (+bv).  Output layout V[slice][c][j]
// ---------------------------------------------------------------------------
__global__ __launch_bounds__(256) void v_proj(
    const float* __restrict__ x2,
    const float* __restrict__ wv1, const float* __restrict__ bv1,
    const float* __restrict__ wv2, const float* __restrict__ bv2,
    u16* __restrict__ wsV)
{
    __shared__ float w_lds[64 * 128];
    const int jt = blockIdx.x;
    const int ct = blockIdx.y;
    const int s  = blockIdx.z;
    const int branch = s >> 2, b = s & 3;
    const float* w    = branch ? wv2 : wv1;
    const float* bias = branch ? bv2 : bv1;
    u16* dst = wsV + (size_t)s * C_DIM * N_TOK;

    const int tid = threadIdx.x;
    const int jl = tid & 63;
    const int cb = tid >> 6;                 // 0..3 -> c = ct*64 + cb*16 + mm
    const float* xc = x2 + (size_t)b * C_DIM * N_TOK + jt * 64 + jl;

    float acc[16];
#pragma unroll
    for (int mm = 0; mm < 16; ++mm) acc[mm] = 0.f;

    for (int p = 0; p < 2; ++p) {
        __syncthreads();
        for (int t = tid; t < 64 * 128; t += 256) {
            const int row = t >> 7, col = t & 127;
            w_lds[t] = w[(size_t)(ct * 64 + row) * 256 + p * 128 + col];
        }
        __syncthreads();
        for (int c4 = 0; c4 < 128; c4 += 4) {
            const float xv0 = xc[(size_t)(p * 128 + c4 + 0) * N_TOK];
            const float xv1 = xc[(size_t)(p * 128 + c4 + 1) * N_TOK];
            const float xv2 = xc[(size_t)(p * 128 + c4 + 2) * N_TOK];
            const float xv3 = xc[(size_t)(p * 128 + c4 + 3) * N_TOK];
#pragma unroll
            for (int mm = 0; mm < 16; ++mm) {
                const float4 wv = *(const float4*)&w_lds[(cb * 16 + mm) * 128 + c4];
                acc[mm] += xv0 * wv.x + xv1 * wv.y + xv2 * wv.z + xv3 * wv.w;
            }
        }
    }
#pragma unroll
    for (int mm = 0; mm < 16; ++mm) {
        const int c = ct * 64 + cb * 16 + mm;
        dst[(size_t)c * N_TOK + jt * 64 + jl] = f2bf(acc[mm] + bias[c]);
    }
}

// ---------------------------------------------------------------------------
// Kernel 3: flash attention, R=2 (each wave owns 32 i-rows = 2 Q-tiles).
// Q,K: [slice][row][32] bf16 ; V: [slice][c][j] bf16 ; O: [slice][i][c] bf16
// grid 256 1-D: n = slice + 8*iblock (slice -> XCD affinity), block 256
// V LDS layout: row c (32 j = 64B), 16B-blocks XOR-swizzled: pos = pair^(c&3)
// ---------------------------------------------------------------------------
__device__ __forceinline__ void stage_v(const u16* vslice, short* lds_dst_base,
                                        int wave, int lane, int j0)
{
    // lane l fills LDS row crow+(l>>2), 16B-block position (l&3).
    // content must be global chunk-pair cp = (l&3) ^ (row&3); crow%4==0
    const int cp = (lane & 3) ^ ((lane >> 2) & 3);
#pragma unroll
    for (int ii = 0; ii < 4; ++ii) {
        const int crow = wave * 64 + ii * 16;
        const u16* gp = vslice + (size_t)(crow + (lane >> 2)) * N_TOK + j0 + cp * 8;
        short* lp = lds_dst_base + crow * 32;   // linear dest: 64B per c-row
        __builtin_amdgcn_global_load_lds(
            (const __attribute__((address_space(1))) void*)gp,
            (__attribute__((address_space(3))) void*)lp, 16, 0, 0);
    }
}

__global__ __launch_bounds__(256, 1) void attn_fwd(
    const u16* __restrict__ Q, const u16* __restrict__ K,
    const u16* __restrict__ V, u16* __restrict__ O)
{
    __shared__ short vlds[2 * 8192];   // 2 x (256 c x 32 j) bf16 = 32 KB

    const int n  = blockIdx.x;
    const int s  = n & 7;              // slice: same slice -> same XCD (n%8)
    const int ib = n >> 3;             // i-block of 128 rows
    const u16* q = Q + (size_t)s * N_TOK * D_DIM;
    const u16* k = K + (size_t)s * N_TOK * D_DIM;
    const u16* v = V + (size_t)s * C_DIM * N_TOK;
    u16*       o = O + (size_t)s * N_TOK * C_DIM;

    const int tid  = threadIdx.x;
    const int wave = tid >> 6;
    const int lane = tid & 63;
    const int g    = lane >> 4;
    const int li   = lane & 15;
    const int i0   = ib * 128 + wave * 32;

    // two Q fragments (B operand): lane li -> rows i0+li, i0+16+li
    short8 qf[2];
    qf[0] = *(const short8*)(q + (size_t)(i0 + li) * D_DIM + 8 * g);
    qf[1] = *(const short8*)(q + (size_t)(i0 + 16 + li) * D_DIM + 8 * g);

    f32x4 acc[2][16];
#pragma unroll
    for (int it = 0; it < 2; ++it)
#pragma unroll
        for (int cf = 0; cf < 16; ++cf) acc[it][cf] = (f32x4){0.f, 0.f, 0.f, 0.f};
    float m[2] = {-3.0e38f, -3.0e38f}, lsum[2] = {0.f, 0.f};

    // swizzled V-fragment offsets (shorts), loop-invariant parts:
    // lo: block pos (g>>1)^(li&3), half g&1 ; hi: pos ((g>>1)^2)^(li&3)
    const int p_lo = ((((g >> 1)    ) ^ (li & 3)) << 3) + (g & 1) * 4;
    const int p_hi = ((((g >> 1) ^ 2) ^ (li & 3)) << 3) + (g & 1) * 4;

    stage_v(v, vlds, wave, lane, 0);
    __syncthreads();

    int buf = 0;
    for (int t = 0; t < N_TOK / 32; ++t) {
        if (t < N_TOK / 32 - 1) stage_v(v, vlds + (buf ^ 1) * 8192, wave, lane, (t + 1) * 32);
        const int j0 = t * 32;

        // K fragments shared by both Q-tiles
        const short8 kf0 = *(const short8*)(k + (size_t)(j0 + li) * D_DIM + 8 * g);
        const short8 kf1 = *(const short8*)(k + (size_t)(j0 + 16 + li) * D_DIM + 8 * g);
        const f32x4 z = (f32x4){0.f, 0.f, 0.f, 0.f};

        short8 pa[2];
#pragma unroll
        for (int it = 0; it < 2; ++it) {
            // S^T = K * Q^T : D[j-row][i-col], i = li lane-local
            f32x4 s0 = __builtin_amdgcn_mfma_f32_16x16x32_bf16(kf0, qf[it], z, 0, 0, 0);
            f32x4 s1 = __builtin_amdgcn_mfma_f32_16x16x32_bf16(kf1, qf[it], z, 0, 0, 0);

            float pm = fmaxf(fmaxf(fmaxf(s0[0], s0[1]), fmaxf(s0[2], s0[3])),
                             fmaxf(fmaxf(s1[0], s1[1]), fmaxf(s1[2], s1[3])));
            pm = fmaxf(pm, __shfl_xor(pm, 16));
            pm = fmaxf(pm, __shfl_xor(pm, 32));

            if (__any(pm > m[it] + 8.0f)) {      // T13 defer-max
                const float mn = fmaxf(m[it], pm);
                const float sc = __expf(m[it] - mn);
                m[it] = mn;
                lsum[it] *= sc;
                float scr[4];
#pragma unroll
                for (int r = 0; r < 4; ++r) scr[r] = __shfl(sc, 4 * g + r);
#pragma unroll
                for (int cf = 0; cf < 16; ++cf)
#pragma unroll
                    for (int r = 0; r < 4; ++r) acc[it][cf][r] *= scr[r];
            }

            float p[8];
#pragma unroll
            for (int r = 0; r < 4; ++r) {
                p[r]     = __expf(s0[r] - m[it]);
                p[4 + r] = __expf(s1[r] - m[it]);
            }
            float rs = (p[0] + p[1]) + (p[2] + p[3]) + (p[4] + p[5]) + (p[6] + p[7]);
            rs += __shfl_xor(rs, 16);
            rs += __shfl_xor(rs, 32);
            lsum[it] += rs;

#pragma unroll
            for (int jj = 0; jj < 8; ++jj) pa[it][jj] = (short)f2bf(p[jj]);
        }

        // O += P * V^T ; each V fragment feeds both i-tiles (R=2 reuse)
        const int vb = buf * 8192;
#pragma unroll
        for (int cf = 0; cf < 16; ++cf) {
            const int ro = vb + (cf * 16 + li) * 32;
            const short4v lo = *(const short4v*)&vlds[ro + p_lo];
            const short4v hi = *(const short4v*)&vlds[ro + p_hi];
            const short8 vf = {lo[0], lo[1], lo[2], lo[3], hi[0], hi[1], hi[2], hi[3]};
            acc[0][cf] = __builtin_amdgcn_mfma_f32_16x16x32_bf16(pa[0], vf, acc[0][cf], 0, 0, 0);
            acc[1][cf] = __builtin_amdgcn_mfma_f32_16x16x32_bf16(pa[1], vf, acc[1][cf], 0, 0, 0);
        }
        __syncthreads();
        buf ^= 1;
    }

    // normalize and store O[i][c]
#pragma unroll
    for (int it = 0; it < 2; ++it) {
        const float linv = 1.0f / lsum[it];
        float lr[4];
#pragma unroll
        for (int r = 0; r < 4; ++r) lr[r] = __shfl(linv, 4 * g + r);
#pragma unroll
        for (int cf = 0; cf < 16; ++cf)
#pragma unroll
            for (int r = 0; r < 4; ++r)
                o[(size_t)(i0 + it * 16 + 4 * g + r) * C_DIM + cf * 16 + li] =
                    f2bf(acc[it][cf][r] * lr[r]);
    }
}

// ---------------------------------------------------------------------------
// Kernel 4: out[b][c][i] = x1 + x2 + O1[b][i][c] + O2[b][i][c]  (LDS transpose)
// ---------------------------------------------------------------------------
__global__ __launch_bounds__(256) void epilogue(
    const float* __restrict__ x1, const float* __restrict__ x2,
    const u16* __restrict__ O, float* __restrict__ out)
{
    __shared__ float tl[64][65];
    const int it = blockIdx.x, ct = blockIdx.y, b = blockIdx.z;
    const int tid = threadIdx.x;
    const int cl = tid & 63, r0 = tid >> 6;

    const u16* O1 = O + (size_t)(b)     * N_TOK * C_DIM;
    const u16* O2 = O + (size_t)(4 + b) * N_TOK * C_DIM;

#pragma unroll
    for (int rr = 0; rr < 16; ++rr) {
        const int il = r0 + rr * 4;
        const size_t off = (size_t)(it * 64 + il) * C_DIM + ct * 64 + cl;
        tl[il][cl] = bf2f(O1[off]) + bf2f(O2[off]);
    }
    __syncthreads();
#pragma unroll
    for (int rr = 0; rr < 16; ++rr) {
        const int c2 = r0 + rr * 4;
        const size_t idx = ((size_t)b * C_DIM + ct * 64 + c2) * N_TOK + it * 64 + cl;
        out[idx] = x1[idx] + x2[idx] + tl[cl][c2];
    }
}

// ---------------------------------------------------------------------------
extern "C" void kernel_launch(void* const* d_in, const int* in_sizes, int n_in,
                              void* d_out, int out_size, void* d_ws, size_t ws_size,
                              hipStream_t stream)
{
    const float* x1  = (const float*)d_in[0];
    const float* x2  = (const float*)d_in[1];
    const float* wq1 = (const float*)d_in[2];
    const float* bq1 = (const float*)d_in[3];
    const float* wk1 = (const float*)d_in[4];
    const float* bk1 = (const float*)d_in[5];
    const float* wv1 = (const float*)d_in[6];
    const float* bv1 = (const float*)d_in[7];
    const float* wq2 = (const float*)d_in[8];
    const float* bq2 = (const float*)d_in[9];
    const float* wk2 = (const float*)d_in[10];
    const float* bk2 = (const float*)d_in[11];
    const float* wv2 = (const float*)d_in[12];
    const float* bv2 = (const float*)d_in[13];
    float* out = (float*)d_out;

    // ws layout (bf16 elements): Q[8][4096][32] | K[8][4096][32] | V[8][256][4096] | O[8][4096][256]
    u16* wsQ = (u16*)d_ws;
    u16* wsK = wsQ + (size_t)8 * N_TOK * D_DIM;
    u16* wsV = wsK + (size_t)8 * N_TOK * D_DIM;
    u16* wsO = wsV + (size_t)8 * C_DIM * N_TOK;

    qk_proj<<<dim3(64, 16), 256, 0, stream>>>(x1, x2, wq1, bq1, wk1, bk1,
                                              wq2, bq2, wk2, bk2, wsQ, wsK);
    v_proj<<<dim3(64, 4, 8), 256, 0, stream>>>(x2, wv1, bv1, wv2, bv2, wsV);
    attn_fwd<<<dim3(256), 256, 0, stream>>>(wsQ, wsK, wsV, wsO);
    epilogue<<<dim3(64, 4, 4), 256, 0, stream>>>(x1, x2, wsO, out);
}

// Round 3
// 262.603 us; speedup vs baseline: 2.2722x; 1.4820x over previous
//
#include <hip/hip_runtime.h>

// Problem constants
#define N_TOK 4096   // H*W
#define C_DIM 256
#define D_DIM 32
#define B_SZ  4

typedef float f32x4 __attribute__((ext_vector_type(4)));
typedef short short8 __attribute__((ext_vector_type(8)));
typedef short short4v __attribute__((ext_vector_type(4)));
typedef unsigned short u16;

__device__ __forceinline__ u16 f2bf(float f) {
    unsigned int u = __builtin_bit_cast(unsigned int, f);
    u += 0x7fffu + ((u >> 16) & 1u);   // round-to-nearest-even
    return (u16)(u >> 16);
}
__device__ __forceinline__ u16 f2bf_fast(float f) {   // round-half-up (p >= 0)
    return (u16)((__builtin_bit_cast(unsigned int, f) + 0x8000u) >> 16);
}
__device__ __forceinline__ float bf2f(u16 h) {
    unsigned int u = ((unsigned int)h) << 16;
    return __builtin_bit_cast(float, u);
}

// ---------------------------------------------------------------------------
// Kernel 1: q/k projection.  q = wq*x1 (+bq), k = wk*x2 (+bk)
// Output layout: Q[slice][i][d], K[slice][j][d]  (d contiguous, bf16)
// ---------------------------------------------------------------------------
__global__ __launch_bounds__(256) void qk_proj(
    const float* __restrict__ x1, const float* __restrict__ x2,
    const float* __restrict__ wq1, const float* __restrict__ bq1,
    const float* __restrict__ wk1, const float* __restrict__ bk1,
    const float* __restrict__ wq2, const float* __restrict__ bq2,
    const float* __restrict__ wk2, const float* __restrict__ bk2,
    u16* __restrict__ wsQ, u16* __restrict__ wsK)
{
    __shared__ float w_lds[32 * 256];
    const int ib = blockIdx.x;
    const int comb = blockIdx.y;
    const int b = comb & 3;
    const int branch = (comb >> 2) & 1;
    const int qk = comb >> 3;

    const float* x = qk ? x2 : x1;           // q from x1; k from x2
    const float* w; const float* bias; u16* dst;
    if (qk == 0) { w = branch ? wq2 : wq1; bias = branch ? bq2 : bq1; dst = wsQ; }
    else         { w = branch ? wk2 : wk1; bias = branch ? bk2 : bk1; dst = wsK; }
    const int slice = branch * 4 + b;
    dst += (size_t)slice * N_TOK * D_DIM;

    const int tid = threadIdx.x;
    for (int t = tid; t < 32 * 256; t += 256) w_lds[t] = w[t];
    __syncthreads();

    const int il = tid & 63;
    const int db = tid >> 6;                 // 0..3 -> d = db*8 + mm
    const float* xc = x + (size_t)b * C_DIM * N_TOK + ib * 64 + il;

    float acc[8] = {0.f,0.f,0.f,0.f,0.f,0.f,0.f,0.f};
    for (int c4 = 0; c4 < 256; c4 += 4) {
        const float xv0 = xc[(size_t)(c4 + 0) * N_TOK];
        const float xv1 = xc[(size_t)(c4 + 1) * N_TOK];
        const float xv2 = xc[(size_t)(c4 + 2) * N_TOK];
        const float xv3 = xc[(size_t)(c4 + 3) * N_TOK];
#pragma unroll
        for (int mm = 0; mm < 8; ++mm) {
            const float4 wv = *(const float4*)&w_lds[(db * 8 + mm) * 256 + c4];
            acc[mm] += xv0 * wv.x + xv1 * wv.y + xv2 * wv.z + xv3 * wv.w;
        }
    }
    short8 pack;
#pragma unroll
    for (int mm = 0; mm < 8; ++mm)
        pack[mm] = (short)f2bf(acc[mm] + bias[db * 8 + mm]);
    *(short8*)(dst + (size_t)(ib * 64 + il) * D_DIM + db * 8) = pack;
}

// ---------------------------------------------------------------------------
// Kernel 2: v projection.  v = wv*x2 (+bv).  Output layout V[slice][c][j]
// ---------------------------------------------------------------------------
__global__ __launch_bounds__(256) void v_proj(
    const float* __restrict__ x2,
    const float* __restrict__ wv1, const float* __restrict__ bv1,
    const float* __restrict__ wv2, const float* __restrict__ bv2,
    u16* __restrict__ wsV)
{
    __shared__ float w_lds[64 * 128];
    const int jt = blockIdx.x;
    const int ct = blockIdx.y;
    const int s  = blockIdx.z;
    const int branch = s >> 2, b = s & 3;
    const float* w    = branch ? wv2 : wv1;
    const float* bias = branch ? bv2 : bv1;
    u16* dst = wsV + (size_t)s * C_DIM * N_TOK;

    const int tid = threadIdx.x;
    const int jl = tid & 63;
    const int cb = tid >> 6;                 // 0..3 -> c = ct*64 + cb*16 + mm
    const float* xc = x2 + (size_t)b * C_DIM * N_TOK + jt * 64 + jl;

    float acc[16];
#pragma unroll
    for (int mm = 0; mm < 16; ++mm) acc[mm] = 0.f;

    for (int p = 0; p < 2; ++p) {
        __syncthreads();
        for (int t = tid; t < 64 * 128; t += 256) {
            const int row = t >> 7, col = t & 127;
            w_lds[t] = w[(size_t)(ct * 64 + row) * 256 + p * 128 + col];
        }
        __syncthreads();
        for (int c4 = 0; c4 < 128; c4 += 4) {
            const float xv0 = xc[(size_t)(p * 128 + c4 + 0) * N_TOK];
            const float xv1 = xc[(size_t)(p * 128 + c4 + 1) * N_TOK];
            const float xv2 = xc[(size_t)(p * 128 + c4 + 2) * N_TOK];
            const float xv3 = xc[(size_t)(p * 128 + c4 + 3) * N_TOK];
#pragma unroll
            for (int mm = 0; mm < 16; ++mm) {
                const float4 wv = *(const float4*)&w_lds[(cb * 16 + mm) * 128 + c4];
                acc[mm] += xv0 * wv.x + xv1 * wv.y + xv2 * wv.z + xv3 * wv.w;
            }
        }
    }
#pragma unroll
    for (int mm = 0; mm < 16; ++mm) {
        const int c = ct * 64 + cb * 16 + mm;
        dst[(size_t)c * N_TOK + jt * 64 + jl] = f2bf(acc[mm] + bias[c]);
    }
}

// ---------------------------------------------------------------------------
// Kernel 3: flash attention.  8 waves = 2 j-groups x 4 waves; R=2 (32 i/wave).
// Q,K: [slice][row][32] bf16 ; V: [slice][c][j] bf16 ; O: [slice][i][c] bf16
// grid 256 1-D: n = slice + 8*iblock, block 512.
// V LDS tile 256c x 32j per group, double-buffered; 16B chunks XOR-swizzled
// with the row's UPPER bits: stored pos = q ^ ((row>>2)&3)  -> 2-way min.
// ---------------------------------------------------------------------------
__device__ __forceinline__ void stage_v(const u16* vslice, short* lds_dst_base,
                                        int wg, int lane, int j0)
{
    // lane l writes LDS (row crow+(l>>2), pos l&3); content = chunk (l&3)^(l>>4)
    const int cp = (lane & 3) ^ (lane >> 4);
#pragma unroll
    for (int ii = 0; ii < 4; ++ii) {
        const int crow = wg * 64 + ii * 16;
        const u16* gp = vslice + (size_t)(crow + (lane >> 2)) * N_TOK + j0 + cp * 8;
        short* lp = lds_dst_base + crow * 32;   // linear dest: 64B per c-row
        __builtin_amdgcn_global_load_lds(
            (const __attribute__((address_space(1))) void*)gp,
            (__attribute__((address_space(3))) void*)lp, 16, 0, 0);
    }
}

__global__ __launch_bounds__(512, 2) void attn_fwd(
    const u16* __restrict__ Q, const u16* __restrict__ K,
    const u16* __restrict__ V, u16* __restrict__ O)
{
    __shared__ short vlds[2][2][8192];          // [grp][buf][256c x 32j] = 64 KB
    __shared__ float mlscr[2][4][64][2][2];     // [grp][wg][lane][it][{m,l}] 8 KB

    const int n  = blockIdx.x;
    const int s  = n & 7;              // slice: same slice -> same XCD (n%8)
    const int ib = n >> 3;             // i-block of 128 rows
    const u16* q = Q + (size_t)s * N_TOK * D_DIM;
    const u16* k = K + (size_t)s * N_TOK * D_DIM;
    const u16* v = V + (size_t)s * C_DIM * N_TOK;
    u16*       o = O + (size_t)s * N_TOK * C_DIM;

    const int tid  = threadIdx.x;
    const int wave = tid >> 6;
    const int lane = tid & 63;
    const int grp  = wave >> 2;        // j-half
    const int wg   = wave & 3;
    const int g    = lane >> 4;
    const int li   = lane & 15;
    const int i0   = ib * 128 + wg * 32;
    const int jbase = grp * (N_TOK / 2);
    const int NT = N_TOK / 2 / 32;     // 64 tiles per group

    short8 qf[2];
    qf[0] = *(const short8*)(q + (size_t)(i0 + li) * D_DIM + 8 * g);
    qf[1] = *(const short8*)(q + (size_t)(i0 + 16 + li) * D_DIM + 8 * g);

    f32x4 acc[2][16];
#pragma unroll
    for (int it = 0; it < 2; ++it)
#pragma unroll
        for (int cf = 0; cf < 16; ++cf) acc[it][cf] = (f32x4){0.f, 0.f, 0.f, 0.f};
    float m[2] = {-3.0e38f, -3.0e38f}, lsum[2] = {0.f, 0.f};

    // swizzled V-fragment short-offsets within a row (row-term applied at read)
    const int hq   = li >> 2;
    const int p_lo = ((((g >> 1)    ) ^ hq) << 3) + (g & 1) * 4;
    const int p_hi = ((((g >> 1) ^ 2) ^ hq) << 3) + (g & 1) * 4;

    // prologue: K regs + V tile for t=0
    short8 kf0 = *(const short8*)(k + (size_t)(jbase + li) * D_DIM + 8 * g);
    short8 kf1 = *(const short8*)(k + (size_t)(jbase + 16 + li) * D_DIM + 8 * g);
    stage_v(v, &vlds[grp][0][0], wg, lane, jbase);
    __syncthreads();

    int buf = 0;
    for (int t = 0; t < NT; ++t) {
        short8 kn0, kn1;
        if (t < NT - 1) {               // prefetch next K (regs) + V (LDS)
            const int jn = jbase + (t + 1) * 32;
            kn0 = *(const short8*)(k + (size_t)(jn + li) * D_DIM + 8 * g);
            kn1 = *(const short8*)(k + (size_t)(jn + 16 + li) * D_DIM + 8 * g);
            stage_v(v, &vlds[grp][buf ^ 1][0], wg, lane, jn);
        }

        const f32x4 z = (f32x4){0.f, 0.f, 0.f, 0.f};
        short8 pa[2];
#pragma unroll
        for (int it = 0; it < 2; ++it) {
            // S^T = K * Q^T : D[j-row][i-col], i = li lane-local
            f32x4 s0 = __builtin_amdgcn_mfma_f32_16x16x32_bf16(kf0, qf[it], z, 0, 0, 0);
            f32x4 s1 = __builtin_amdgcn_mfma_f32_16x16x32_bf16(kf1, qf[it], z, 0, 0, 0);

            float pm = fmaxf(fmaxf(fmaxf(s0[0], s0[1]), fmaxf(s0[2], s0[3])),
                             fmaxf(fmaxf(s1[0], s1[1]), fmaxf(s1[2], s1[3])));
            pm = fmaxf(pm, __shfl_xor(pm, 16));
            pm = fmaxf(pm, __shfl_xor(pm, 32));

            if (__any(pm > m[it] + 8.0f)) {      // T13 defer-max
                const float mn = fmaxf(m[it], pm);
                const float sc = __expf(m[it] - mn);
                m[it] = mn;
                lsum[it] *= sc;
                float scr[4];
#pragma unroll
                for (int r = 0; r < 4; ++r) scr[r] = __shfl(sc, 4 * g + r);
#pragma unroll
                for (int cf = 0; cf < 16; ++cf)
#pragma unroll
                    for (int r = 0; r < 4; ++r) acc[it][cf][r] *= scr[r];
            }

            float p[8];
#pragma unroll
            for (int r = 0; r < 4; ++r) {
                p[r]     = __expf(s0[r] - m[it]);
                p[4 + r] = __expf(s1[r] - m[it]);
            }
            float rs = (p[0] + p[1]) + (p[2] + p[3]) + (p[4] + p[5]) + (p[6] + p[7]);
            rs += __shfl_xor(rs, 16);
            rs += __shfl_xor(rs, 32);
            lsum[it] += rs;

#pragma unroll
            for (int jj = 0; jj < 8; ++jj) pa[it][jj] = (short)f2bf_fast(p[jj]);
        }

        // O += P * V^T ; V fragment feeds both i-tiles (R=2)
        const short* vb = &vlds[grp][buf][0];
#pragma unroll
        for (int cf = 0; cf < 16; ++cf) {
            const int ro = (cf * 16 + li) * 32;
            const short4v lo = *(const short4v*)&vb[ro + p_lo];
            const short4v hi = *(const short4v*)&vb[ro + p_hi];
            const short8 vf = {lo[0], lo[1], lo[2], lo[3], hi[0], hi[1], hi[2], hi[3]};
            acc[0][cf] = __builtin_amdgcn_mfma_f32_16x16x32_bf16(pa[0], vf, acc[0][cf], 0, 0, 0);
            acc[1][cf] = __builtin_amdgcn_mfma_f32_16x16x32_bf16(pa[1], vf, acc[1][cf], 0, 0, 0);
        }
        __syncthreads();
        buf ^= 1;
        if (t < NT - 1) { kf0 = kn0; kf1 = kn1; }
    }

    // ---- merge the two j-group partials (flash combine) ----
#pragma unroll
    for (int it = 0; it < 2; ++it) {
        mlscr[grp][wg][lane][it][0] = m[it];
        mlscr[grp][wg][lane][it][1] = lsum[it];
    }
    __syncthreads();

    float linv[2];
#pragma unroll
    for (int it = 0; it < 2; ++it) {
        const float mo = mlscr[grp ^ 1][wg][lane][it][0];
        const float lo = mlscr[grp ^ 1][wg][lane][it][1];
        const float M  = fmaxf(m[it], mo);
        const float sc = __expf(m[it] - M);
        const float so = __expf(mo - M);
        linv[it] = 1.0f / (lsum[it] * sc + lo * so);
        float scr[4];
#pragma unroll
        for (int r = 0; r < 4; ++r) scr[r] = __shfl(sc, 4 * g + r);
#pragma unroll
        for (int cf = 0; cf < 16; ++cf)
#pragma unroll
            for (int r = 0; r < 4; ++r) acc[it][cf][r] *= scr[r];
    }

    f32x4* pv = (f32x4*)&vlds[0][0][0];   // reuse 64 KB as merge scratch
#pragma unroll
    for (int it = 0; it < 2; ++it) {
        __syncthreads();
        if (grp == 1) {
#pragma unroll
            for (int cf = 0; cf < 16; ++cf)
                pv[(cf * 4 + wg) * 64 + lane] = acc[it][cf];
        }
        __syncthreads();
        if (grp == 0) {
#pragma unroll
            for (int cf = 0; cf < 16; ++cf) {
                const f32x4 o4 = pv[(cf * 4 + wg) * 64 + lane];
                acc[it][cf][0] += o4[0]; acc[it][cf][1] += o4[1];
                acc[it][cf][2] += o4[2]; acc[it][cf][3] += o4[3];
            }
        }
    }

    if (grp == 0) {
#pragma unroll
        for (int it = 0; it < 2; ++it) {
            float lr[4];
#pragma unroll
            for (int r = 0; r < 4; ++r) lr[r] = __shfl(linv[it], 4 * g + r);
#pragma unroll
            for (int cf = 0; cf < 16; ++cf)
#pragma unroll
                for (int r = 0; r < 4; ++r)
                    o[(size_t)(i0 + it * 16 + 4 * g + r) * C_DIM + cf * 16 + li] =
                        f2bf(acc[it][cf][r] * lr[r]);
        }
    }
}

// ---------------------------------------------------------------------------
// Kernel 4: out[b][c][i] = x1 + x2 + O1[b][i][c] + O2[b][i][c]  (LDS transpose)
// ---------------------------------------------------------------------------
__global__ __launch_bounds__(256) void epilogue(
    const float* __restrict__ x1, const float* __restrict__ x2,
    const u16* __restrict__ O, float* __restrict__ out)
{
    __shared__ float tl[64][65];
    const int it = blockIdx.x, ct = blockIdx.y, b = blockIdx.z;
    const int tid = threadIdx.x;
    const int cl = tid & 63, r0 = tid >> 6;

    const u16* O1 = O + (size_t)(b)     * N_TOK * C_DIM;
    const u16* O2 = O + (size_t)(4 + b) * N_TOK * C_DIM;

#pragma unroll
    for (int rr = 0; rr < 16; ++rr) {
        const int il = r0 + rr * 4;
        const size_t off = (size_t)(it * 64 + il) * C_DIM + ct * 64 + cl;
        tl[il][cl] = bf2f(O1[off]) + bf2f(O2[off]);
    }
    __syncthreads();
#pragma unroll
    for (int rr = 0; rr < 16; ++rr) {
        const int c2 = r0 + rr * 4;
        const size_t idx = ((size_t)b * C_DIM + ct * 64 + c2) * N_TOK + it * 64 + cl;
        out[idx] = x1[idx] + x2[idx] + tl[cl][c2];
    }
}

// ---------------------------------------------------------------------------
extern "C" void kernel_launch(void* const* d_in, const int* in_sizes, int n_in,
                              void* d_out, int out_size, void* d_ws, size_t ws_size,
                              hipStream_t stream)
{
    const float* x1  = (const float*)d_in[0];
    const float* x2  = (const float*)d_in[1];
    const float* wq1 = (const float*)d_in[2];
    const float* bq1 = (const float*)d_in[3];
    const float* wk1 = (const float*)d_in[4];
    const float* bk1 = (const float*)d_in[5];
    const float* wv1 = (const float*)d_in[6];
    const float* bv1 = (const float*)d_in[7];
    const float* wq2 = (const float*)d_in[8];
    const float* bq2 = (const float*)d_in[9];
    const float* wk2 = (const float*)d_in[10];
    const float* bk2 = (const float*)d_in[11];
    const float* wv2 = (const float*)d_in[12];
    const float* bv2 = (const float*)d_in[13];
    float* out = (float*)d_out;

    // ws layout (bf16): Q[8][4096][32] | K[8][4096][32] | V[8][256][4096] | O[8][4096][256]
    u16* wsQ = (u16*)d_ws;
    u16* wsK = wsQ + (size_t)8 * N_TOK * D_DIM;
    u16* wsV = wsK + (size_t)8 * N_TOK * D_DIM;
    u16* wsO = wsV + (size_t)8 * C_DIM * N_TOK;

    qk_proj<<<dim3(64, 16), 256, 0, stream>>>(x1, x2, wq1, bq1, wk1, bk1,
                                              wq2, bq2, wk2, bk2, wsQ, wsK);
    v_proj<<<dim3(64, 4, 8), 256, 0, stream>>>(x2, wv1, bv1, wv2, bv2, wsV);
    attn_fwd<<<dim3(256), 512, 0, stream>>>(wsQ, wsK, wsV, wsO);
    epilogue<<<dim3(64, 4, 4), 256, 0, stream>>>(x1, x2, wsO, out);
}

// Round 5
// 170.196 us; speedup vs baseline: 3.5060x; 1.5429x over previous
//
#include <hip/hip_runtime.h>

// Problem constants
#define N_TOK 4096   // H*W
#define C_DIM 256
#define D_DIM 32

typedef float f32x4 __attribute__((ext_vector_type(4)));
typedef short short8 __attribute__((ext_vector_type(8)));
typedef unsigned short u16;

__device__ __forceinline__ u16 f2bf(float f) {
    unsigned int u = __builtin_bit_cast(unsigned int, f);
    u += 0x7fffu + ((u >> 16) & 1u);   // round-to-nearest-even
    return (u16)(u >> 16);
}
__device__ __forceinline__ u16 f2bf_fast(float f) {   // round-half-up (f >= 0)
    return (u16)((__builtin_bit_cast(unsigned int, f) + 0x8000u) >> 16);
}
__device__ __forceinline__ float bf2f(u16 h) {
    unsigned int u = ((unsigned int)h) << 16;
    return __builtin_bit_cast(float, u);
}
__device__ __forceinline__ float exp2_fast(float x) {  // 2^x, compiler-managed
#if __has_builtin(__builtin_amdgcn_exp2f)
    return __builtin_amdgcn_exp2f(x);
#else
    return exp2f(x);
#endif
}

// ---------------------------------------------------------------------------
// Kernel 1: q/k projection.  q = (wq*x1 + bq)*log2e  (exp2-domain fold),
//           k = wk*x2 + bk
// Output layout: Q[slice][i][d], K[slice][j][d]  (d contiguous, bf16)
// ---------------------------------------------------------------------------
__global__ __launch_bounds__(256) void qk_proj(
    const float* __restrict__ x1, const float* __restrict__ x2,
    const float* __restrict__ wq1, const float* __restrict__ bq1,
    const float* __restrict__ wk1, const float* __restrict__ bk1,
    const float* __restrict__ wq2, const float* __restrict__ bq2,
    const float* __restrict__ wk2, const float* __restrict__ bk2,
    u16* __restrict__ wsQ, u16* __restrict__ wsK)
{
    __shared__ float w_lds[32 * 256];
    const int ib = blockIdx.x;
    const int comb = blockIdx.y;
    const int b = comb & 3;
    const int branch = (comb >> 2) & 1;
    const int qk = comb >> 3;

    const float* x = qk ? x2 : x1;           // q from x1; k from x2
    const float* w; const float* bias; u16* dst;
    if (qk == 0) { w = branch ? wq2 : wq1; bias = branch ? bq2 : bq1; dst = wsQ; }
    else         { w = branch ? wk2 : wk1; bias = branch ? bk2 : bk1; dst = wsK; }
    const int slice = branch * 4 + b;
    dst += (size_t)slice * N_TOK * D_DIM;
    const float osc = (qk == 0) ? 1.44269504088896341f : 1.0f;

    const int tid = threadIdx.x;
    for (int t = tid; t < 32 * 256; t += 256) w_lds[t] = w[t];
    __syncthreads();

    const int il = tid & 63;
    const int db = tid >> 6;                 // 0..3 -> d = db*8 + mm
    const float* xc = x + (size_t)b * C_DIM * N_TOK + ib * 64 + il;

    float acc[8] = {0.f,0.f,0.f,0.f,0.f,0.f,0.f,0.f};
    for (int c4 = 0; c4 < 256; c4 += 4) {
        const float xv0 = xc[(size_t)(c4 + 0) * N_TOK];
        const float xv1 = xc[(size_t)(c4 + 1) * N_TOK];
        const float xv2 = xc[(size_t)(c4 + 2) * N_TOK];
        const float xv3 = xc[(size_t)(c4 + 3) * N_TOK];
#pragma unroll
        for (int mm = 0; mm < 8; ++mm) {
            const float4 wv = *(const float4*)&w_lds[(db * 8 + mm) * 256 + c4];
            acc[mm] += xv0 * wv.x + xv1 * wv.y + xv2 * wv.z + xv3 * wv.w;
        }
    }
    short8 pack;
#pragma unroll
    for (int mm = 0; mm < 8; ++mm)
        pack[mm] = (short)f2bf((acc[mm] + bias[db * 8 + mm]) * osc);
    *(short8*)(dst + (size_t)(ib * 64 + il) * D_DIM + db * 8) = pack;
}

// ---------------------------------------------------------------------------
// Kernel 2: v projection via MFMA.  V[c][j] = sum_k W[c][k] X[k][j] + bias
// block 256 (4 waves, 2x2 wave grid), tile 128c x 128j, K=256 in 8 steps.
// W staged once in LDS (chunk-XOR swizzle); X transposed-staged bf16, dbuf.
// grid (32 jt, 2 ct, 8 slices)
// ---------------------------------------------------------------------------
__device__ __forceinline__ void stage_xt(u16* xtb, const float* xb, int ks,
                                         int wave, int lane)
{
    // XT[j][k] (32 k per buf, 64B rows), chunk kc stored at pos kc ^ ((j>>1)&3)
    const int j  = (wave & 1) * 64 + lane;
    const int cb = (wave >> 1) * 16;       // k (cin) base, 16 per thread
    const float* xp = xb + (size_t)(ks * 32 + cb) * N_TOK + j;
    u16 vals[16];
#pragma unroll
    for (int qq = 0; qq < 16; ++qq) vals[qq] = f2bf(xp[(size_t)qq * N_TOK]);
    const int swz = (j >> 1) & 3;
    u16* row = xtb + j * 32;
    const int c0 = cb >> 3;
    *(short8*)&row[((c0    ) ^ swz) * 8] = *(const short8*)&vals[0];
    *(short8*)&row[((c0 + 1) ^ swz) * 8] = *(const short8*)&vals[8];
}

__global__ __launch_bounds__(256, 2) void v_proj(
    const float* __restrict__ x2,
    const float* __restrict__ wv1, const float* __restrict__ bv1,
    const float* __restrict__ wv2, const float* __restrict__ bv2,
    u16* __restrict__ wsV)
{
    __shared__ __align__(16) u16 wl[128 * 256];     // [c][k] swizzled, 64 KB
    __shared__ __align__(16) u16 xt[2][128 * 32];   // [j][k] swizzled, 16 KB

    const int jt = blockIdx.x, ct = blockIdx.y, s = blockIdx.z;
    const int branch = s >> 2, b = s & 3;
    const float* w    = branch ? wv2 : wv1;
    const float* bias = branch ? bv2 : bv1;
    u16* dst = wsV + (size_t)s * C_DIM * N_TOK;
    const float* xb = x2 + (size_t)b * C_DIM * N_TOK + jt * 128;

    const int tid = threadIdx.x;
    const int wave = tid >> 6, lane = tid & 63;
    const int wr = wave >> 1, wc = wave & 1;
    const int g = lane >> 4, li = lane & 15;

    // ---- stage W[128c][256k] -> bf16 LDS, chunk kc at pos kc ^ (c&7)
    {
        const int c = tid >> 1;
        const int kh = (tid & 1) * 128;
        const float* wrow = w + (size_t)(ct * 128 + c) * C_DIM + kh;
        u16* lrow = wl + c * 256;
#pragma unroll
        for (int kk = 0; kk < 128; kk += 8) {
            const float4 a0 = *(const float4*)&wrow[kk];
            const float4 a1 = *(const float4*)&wrow[kk + 4];
            u16 tmp[8] = {f2bf(a0.x), f2bf(a0.y), f2bf(a0.z), f2bf(a0.w),
                          f2bf(a1.x), f2bf(a1.y), f2bf(a1.z), f2bf(a1.w)};
            const int kc = (kh + kk) >> 3;
            *(short8*)&lrow[(kc ^ (c & 7)) * 8] = *(const short8*)tmp;
        }
    }
    stage_xt(&xt[0][0], xb, 0, wave, lane);
    __syncthreads();

    f32x4 acc[4][4];
#pragma unroll
    for (int mf = 0; mf < 4; ++mf)
#pragma unroll
        for (int nf = 0; nf < 4; ++nf) acc[mf][nf] = (f32x4){0.f, 0.f, 0.f, 0.f};

    int buf = 0;
    for (int ks = 0; ks < 8; ++ks) {
        if (ks < 7) stage_xt(&xt[buf ^ 1][0], xb, ks + 1, wave, lane);

        short8 af[4], bf[4];
#pragma unroll
        for (int mf = 0; mf < 4; ++mf) {
            const int c = wr * 64 + mf * 16 + li;
            af[mf] = *(const short8*)&wl[c * 256 + (((ks * 4 + g) ^ (li & 7)) * 8)];
        }
#pragma unroll
        for (int nf = 0; nf < 4; ++nf) {
            const int j = wc * 64 + nf * 16 + li;
            bf[nf] = *(const short8*)&xt[buf][j * 32 + ((g ^ ((j >> 1) & 3)) * 8)];
        }
        __builtin_amdgcn_s_setprio(1);
#pragma unroll
        for (int mf = 0; mf < 4; ++mf)
#pragma unroll
            for (int nf = 0; nf < 4; ++nf)
                acc[mf][nf] = __builtin_amdgcn_mfma_f32_16x16x32_bf16(
                    af[mf], bf[nf], acc[mf][nf], 0, 0, 0);
        __builtin_amdgcn_s_setprio(0);
        __syncthreads();
        buf ^= 1;
    }

#pragma unroll
    for (int mf = 0; mf < 4; ++mf) {
#pragma unroll
        for (int r = 0; r < 4; ++r) {
            const int c = ct * 128 + wr * 64 + mf * 16 + 4 * g + r;
            const float bv = bias[c];
            u16* drow = dst + (size_t)c * N_TOK + jt * 128;
#pragma unroll
            for (int nf = 0; nf < 4; ++nf)
                drow[wc * 64 + nf * 16 + li] = f2bf(acc[mf][nf][r] + bv);
        }
    }
}

// ---------------------------------------------------------------------------
// Kernel 3: flash attention, static-max exp2 softmax (no online max).
// 8 waves = 2 j-groups x 4 waves; R=2 (32 i-rows/wave); KVBLK=64.
// Q,K: [slice][row][32] bf16 ; V: [slice][c][j] bf16 ; O: [slice][i][c] bf16
// grid 256 1-D: n = slice + 8*iblock (slice -> XCD affinity), block 512.
// V LDS: per group 256c x 64j (128B rows), dbuf; 16B chunk h stored at
// pos = h ^ swz3(row), swz3 = ((row>>2)&3)|((row&1)<<2)  -> conflict-free b128.
// K rows read even/odd interleaved so each lane's 8 P values are j-contiguous.
// ---------------------------------------------------------------------------
__device__ __forceinline__ void stage_v64(const u16* vsl, short* dst,
                                          int wg, int lane, int j0)
{
#pragma unroll
    for (int ii = 0; ii < 8; ++ii) {
        const int rbase = wg * 64 + ii * 8;
        const int row = rbase + (lane >> 3);
        const int swz = ((row >> 2) & 3) | ((row & 1) << 2);
        const int cp = (lane & 7) ^ swz;
        const u16* gp = vsl + (size_t)row * N_TOK + j0 + cp * 8;
        short* lp = dst + rbase * 64;    // linear dest: 8 rows x 128B = 1024B
        __builtin_amdgcn_global_load_lds(
            (const __attribute__((address_space(1))) void*)gp,
            (__attribute__((address_space(3))) void*)lp, 16, 0, 0);
    }
}

__global__ __launch_bounds__(512, 2) void attn_fwd(
    const u16* __restrict__ Q, const u16* __restrict__ K,
    const u16* __restrict__ V, u16* __restrict__ O)
{
    __shared__ __align__(16) short vlds[2][2][256 * 64];  // 128 KB
    __shared__ float lscr[2][4][64][2];                   // 4 KB

    const int n  = blockIdx.x;
    const int s  = n & 7;              // slice: same slice -> same XCD (n%8)
    const int ib = n >> 3;
    const u16* q = Q + (size_t)s * N_TOK * D_DIM;
    const u16* k = K + (size_t)s * N_TOK * D_DIM;
    const u16* v = V + (size_t)s * C_DIM * N_TOK;
    u16*       o = O + (size_t)s * N_TOK * C_DIM;

    const int tid  = threadIdx.x;
    const int wave = tid >> 6;
    const int lane = tid & 63;
    const int grp  = wave >> 2;        // j-half
    const int wg   = wave & 3;
    const int g    = lane >> 4;
    const int li   = lane & 15;
    const int i0   = ib * 128 + wg * 32;
    const int jbase = grp * (N_TOK / 2);
    const int NP = N_TOK / 2 / 64;     // 32 periods

    short8 qf[2];
    qf[0] = *(const short8*)(q + (size_t)(i0 + li) * D_DIM + 8 * g);
    qf[1] = *(const short8*)(q + (size_t)(i0 + 16 + li) * D_DIM + 8 * g);

    f32x4 acc[2][16];
#pragma unroll
    for (int it = 0; it < 2; ++it)
#pragma unroll
        for (int cf = 0; cf < 16; ++cf) acc[it][cf] = (f32x4){0.f, 0.f, 0.f, 0.f};
    float lsum[2] = {0.f, 0.f};

    const int swz3 = ((li >> 2) & 3) | ((li & 1) << 2);

    // prologue: K fragments (even/odd rows per 32-j subtile) + V tile 0
    short8 kf0 = *(const short8*)(k + (size_t)(jbase + 2 * li     ) * D_DIM + 8 * g);
    short8 kf1 = *(const short8*)(k + (size_t)(jbase + 2 * li + 1 ) * D_DIM + 8 * g);
    short8 kf2 = *(const short8*)(k + (size_t)(jbase + 32 + 2 * li) * D_DIM + 8 * g);
    short8 kf3 = *(const short8*)(k + (size_t)(jbase + 33 + 2 * li) * D_DIM + 8 * g);
    stage_v64(v, &vlds[grp][0][0], wg, lane, jbase);
    __syncthreads();

    int buf = 0;
    for (int p = 0; p < NP; ++p) {
        short8 kn0, kn1, kn2, kn3;
        if (p < NP - 1) {
            const int jn = jbase + (p + 1) * 64;
            kn0 = *(const short8*)(k + (size_t)(jn + 2 * li     ) * D_DIM + 8 * g);
            kn1 = *(const short8*)(k + (size_t)(jn + 2 * li + 1 ) * D_DIM + 8 * g);
            kn2 = *(const short8*)(k + (size_t)(jn + 32 + 2 * li) * D_DIM + 8 * g);
            kn3 = *(const short8*)(k + (size_t)(jn + 33 + 2 * li) * D_DIM + 8 * g);
            stage_v64(v, &vlds[grp][buf ^ 1][0], wg, lane, jn);
        }

        const f32x4 z = (f32x4){0.f, 0.f, 0.f, 0.f};
        const short* vb = &vlds[grp][buf][0];
#pragma unroll
        for (int ss = 0; ss < 2; ++ss) {
            const short8 ke = ss ? kf2 : kf0;
            const short8 ko = ss ? kf3 : kf1;
            short8 pa[2];
#pragma unroll
            for (int it = 0; it < 2; ++it) {
                // S'^T: rows j (even: 8g+2r, odd: 8g+2r+1), cols i = li
                f32x4 se = __builtin_amdgcn_mfma_f32_16x16x32_bf16(ke, qf[it], z, 0, 0, 0);
                f32x4 so = __builtin_amdgcn_mfma_f32_16x16x32_bf16(ko, qf[it], z, 0, 0, 0);
                float pe[4], po[4];
#pragma unroll
                for (int r = 0; r < 4; ++r) {
                    pe[r] = exp2_fast(se[r]);   // P = 2^(s*log2e), static shift
                    po[r] = exp2_fast(so[r]);
                }
                lsum[it] += ((pe[0] + po[0]) + (pe[1] + po[1]))
                          + ((pe[2] + po[2]) + (pe[3] + po[3]));
#pragma unroll
                for (int r = 0; r < 4; ++r) {
                    pa[it][2 * r]     = (short)f2bf_fast(pe[r]);
                    pa[it][2 * r + 1] = (short)f2bf_fast(po[r]);
                }
            }
            // O += P * V^T ; one b128 per V fragment, feeds both i-tiles
            __builtin_amdgcn_s_setprio(1);
#pragma unroll
            for (int cf = 0; cf < 16; ++cf) {
                const short8 vf = *(const short8*)
                    &vb[(cf * 16 + li) * 64 + ((((ss << 2) + g) ^ swz3) * 8)];
                acc[0][cf] = __builtin_amdgcn_mfma_f32_16x16x32_bf16(pa[0], vf, acc[0][cf], 0, 0, 0);
                acc[1][cf] = __builtin_amdgcn_mfma_f32_16x16x32_bf16(pa[1], vf, acc[1][cf], 0, 0, 0);
            }
            __builtin_amdgcn_s_setprio(0);
        }
        __syncthreads();
        buf ^= 1;
        if (p < NP - 1) { kf0 = kn0; kf1 = kn1; kf2 = kn2; kf3 = kn3; }
    }

    // cross-lane lsum reduce (once, post-loop) + j-group exchange
#pragma unroll
    for (int it = 0; it < 2; ++it) {
        lsum[it] += __shfl_xor(lsum[it], 16);
        lsum[it] += __shfl_xor(lsum[it], 32);
        lscr[grp][wg][lane][it] = lsum[it];
    }
    __syncthreads();
    float linv[2];
#pragma unroll
    for (int it = 0; it < 2; ++it)
        linv[it] = 1.0f / (lsum[it] + lscr[grp ^ 1][wg][lane][it]);

    // merge accumulators (grp1 -> grp0) via LDS scratch
    f32x4* pv = (f32x4*)&vlds[0][0][0];
#pragma unroll
    for (int it = 0; it < 2; ++it) {
        __syncthreads();
        if (grp == 1) {
#pragma unroll
            for (int cf = 0; cf < 16; ++cf)
                pv[(cf * 4 + wg) * 64 + lane] = acc[it][cf];
        }
        __syncthreads();
        if (grp == 0) {
#pragma unroll
            for (int cf = 0; cf < 16; ++cf) {
                const f32x4 o4 = pv[(cf * 4 + wg) * 64 + lane];
                acc[it][cf][0] += o4[0]; acc[it][cf][1] += o4[1];
                acc[it][cf][2] += o4[2]; acc[it][cf][3] += o4[3];
            }
        }
    }

    if (grp == 0) {
#pragma unroll
        for (int it = 0; it < 2; ++it) {
            float lr[4];
#pragma unroll
            for (int r = 0; r < 4; ++r) lr[r] = __shfl(linv[it], 4 * g + r);
#pragma unroll
            for (int cf = 0; cf < 16; ++cf)
#pragma unroll
                for (int r = 0; r < 4; ++r)
                    o[(size_t)(i0 + it * 16 + 4 * g + r) * C_DIM + cf * 16 + li] =
                        f2bf(acc[it][cf][r] * lr[r]);
        }
    }
}

// ---------------------------------------------------------------------------
// Kernel 4: out[b][c][i] = x1 + x2 + O1[b][i][c] + O2[b][i][c]  (LDS transpose)
// ---------------------------------------------------------------------------
__global__ __launch_bounds__(256) void epilogue(
    const float* __restrict__ x1, const float* __restrict__ x2,
    const u16* __restrict__ O, float* __restrict__ out)
{
    __shared__ float tl[64][65];
    const int it = blockIdx.x, ct = blockIdx.y, b = blockIdx.z;
    const int tid = threadIdx.x;
    const int cl = tid & 63, r0 = tid >> 6;

    const u16* O1 = O + (size_t)(b)     * N_TOK * C_DIM;
    const u16* O2 = O + (size_t)(4 + b) * N_TOK * C_DIM;

#pragma unroll
    for (int rr = 0; rr < 16; ++rr) {
        const int il = r0 + rr * 4;
        const size_t off = (size_t)(it * 64 + il) * C_DIM + ct * 64 + cl;
        tl[il][cl] = bf2f(O1[off]) + bf2f(O2[off]);
    }
    __syncthreads();
#pragma unroll
    for (int rr = 0; rr < 16; ++rr) {
        const int c2 = r0 + rr * 4;
        const size_t idx = ((size_t)b * C_DIM + ct * 64 + c2) * N_TOK + it * 64 + cl;
        out[idx] = x1[idx] + x2[idx] + tl[cl][c2];
    }
}

// ---------------------------------------------------------------------------
extern "C" void kernel_launch(void* const* d_in, const int* in_sizes, int n_in,
                              void* d_out, int out_size, void* d_ws, size_t ws_size,
                              hipStream_t stream)
{
    const float* x1  = (const float*)d_in[0];
    const float* x2  = (const float*)d_in[1];
    const float* wq1 = (const float*)d_in[2];
    const float* bq1 = (const float*)d_in[3];
    const float* wk1 = (const float*)d_in[4];
    const float* bk1 = (const float*)d_in[5];
    const float* wv1 = (const float*)d_in[6];
    const float* bv1 = (const float*)d_in[7];
    const float* wq2 = (const float*)d_in[8];
    const float* bq2 = (const float*)d_in[9];
    const float* wk2 = (const float*)d_in[10];
    const float* bk2 = (const float*)d_in[11];
    const float* wv2 = (const float*)d_in[12];
    const float* bv2 = (const float*)d_in[13];
    float* out = (float*)d_out;

    // ws layout (bf16): Q[8][4096][32] | K[8][4096][32] | V[8][256][4096] | O[8][4096][256]
    u16* wsQ = (u16*)d_ws;
    u16* wsK = wsQ + (size_t)8 * N_TOK * D_DIM;
    u16* wsV = wsK + (size_t)8 * N_TOK * D_DIM;
    u16* wsO = wsV + (size_t)8 * C_DIM * N_TOK;

    qk_proj<<<dim3(64, 16), 256, 0, stream>>>(x1, x2, wq1, bq1, wk1, bk1,
                                              wq2, bq2, wk2, bk2, wsQ, wsK);
    v_proj<<<dim3(32, 2, 8), 256, 0, stream>>>(x2, wv1, bv1, wv2, bv2, wsV);
    attn_fwd<<<dim3(256), 512, 0, stream>>>(wsQ, wsK, wsV, wsO);
    epilogue<<<dim3(64, 4, 4), 256, 0, stream>>>(x1, x2, wsO, out);
}